// Round 1
// baseline (1299.553 us; speedup 1.0000x reference)
//
#include <hip/hip_runtime.h>

#define B_TOT 32768
#define NDW 14
#define NSTEPS 30

typedef __attribute__((ext_vector_type(8))) short short8;
typedef __attribute__((ext_vector_type(4))) float f32x4;

// ---- workspace byte offsets (prep kernel fills, main kernel consumes) ----
// total required ws: 628736 + 512*6*16384 = 50,960,384 bytes (~48.6 MB)
#define WIH_OFF   0           // enc_wih bf16, XOR-swizzled [512][128]
#define WHH_OFF   131072      // enc_whh bf16 plain [512][128]
#define WD_OFF    262144      // dec_wih+dec_whh bf16 plain [512][128]
#define DWHH_OFF  393216      // dec_whh bf16 plain [512][128]
#define FAW_OFF   524288      // fa_w bf16 plain [128][128]
#define WV_OFF    557056      // pooling wv bf16 plain [128][128]
#define WOUT_OFF  589824      // pool_wout bf16 plain [128][128]
#define QK_OFF    622592      // folded (q_tok@wq.T+bq)@wk /sqrt(32), f32 [4][128]
#define EB_OFF    624640      // enc_bih+enc_bhh f32 [512]
#define DB_OFF    626688      // dec_bih+dec_bhh f32 [512]
#define HH_OFF    628736      // h history: [512 tiles][6 slots][16384 B]

// ---- LDS byte offsets (160 KiB exactly) ----
#define XOFF   131072   // x / xw tile [64][128] bf16 swizzled
#define HOFF   147456   // h tile      [64][128] bf16 swizzled
#define SCOFF  98304    // pooling scores [64][4][7] f32 (inside wih region, after 6 hist slots)

__device__ __forceinline__ unsigned short f2bf(float f) {
  unsigned int u = __float_as_uint(f);
  u += 0x7fffu + ((u >> 16) & 1u);
  return (unsigned short)(u >> 16);
}
__device__ __forceinline__ float bf2f(unsigned short h) {
  return __uint_as_float(((unsigned int)h) << 16);
}
__device__ __forceinline__ float sigmf_(float x) { return __builtin_amdgcn_rcpf(1.f + __expf(-x)); }
__device__ __forceinline__ float tanhf_(float x) { return 1.f - 2.f * __builtin_amdgcn_rcpf(1.f + __expf(2.f * x)); }
__device__ __forceinline__ float softplusf_(float x) { return x > 20.f ? x : __logf(1.f + __expf(x)); }
// XOR swizzle: 256 B rows of bf16[128]; spreads 16-row column slices across banks.
__device__ __forceinline__ int swz(int row, int bc) { return row * 256 + (bc ^ ((row & 7) << 4)); }
__device__ __forceinline__ f32x4 splat4(float v) { f32x4 r = {v, v, v, v}; return r; }

// ===================== prep kernel: weight conversion / folding =====================
__global__ void hfn_prep(const float* __restrict__ fa_w,
                         const float* __restrict__ enc_wih, const float* __restrict__ enc_whh,
                         const float* __restrict__ enc_bih, const float* __restrict__ enc_bhh,
                         const float* __restrict__ q_tok,
                         const float* __restrict__ pool_win, const float* __restrict__ pool_bin,
                         const float* __restrict__ pool_wout,
                         const float* __restrict__ dec_wih, const float* __restrict__ dec_whh,
                         const float* __restrict__ dec_bih, const float* __restrict__ dec_bhh,
                         char* __restrict__ ws) {
  const int gt = blockIdx.x * 256 + threadIdx.x;
  const int gs = gridDim.x * 256;
  for (int i = gt; i < 65536; i += gs) {
    const int g = i >> 7, k = i & 127;
    *(unsigned short*)(ws + WIH_OFF + swz(g, 2 * k)) = f2bf(enc_wih[i]);  // pre-swizzled
  }
  for (int i = gt; i < 65536; i += gs) *(unsigned short*)(ws + WHH_OFF + 2 * i) = f2bf(enc_whh[i]);
  for (int i = gt; i < 65536; i += gs) *(unsigned short*)(ws + WD_OFF + 2 * i) = f2bf(dec_wih[i] + dec_whh[i]);
  for (int i = gt; i < 65536; i += gs) *(unsigned short*)(ws + DWHH_OFF + 2 * i) = f2bf(dec_whh[i]);
  for (int i = gt; i < 16384; i += gs) *(unsigned short*)(ws + FAW_OFF + 2 * i) = f2bf(fa_w[i]);
  for (int i = gt; i < 16384; i += gs) *(unsigned short*)(ws + WV_OFF + 2 * i) = f2bf(pool_win[32768 + i]);
  for (int i = gt; i < 16384; i += gs) *(unsigned short*)(ws + WOUT_OFF + 2 * i) = f2bf(pool_wout[i]);
  for (int i = gt; i < 512; i += gs) *(float*)(ws + EB_OFF + 4 * i) = enc_bih[i] + enc_bhh[i];
  for (int i = gt; i < 512; i += gs) *(float*)(ws + DB_OFF + 4 * i) = dec_bih[i] + dec_bhh[i];
  if (blockIdx.x == 0) {
    __shared__ float q[128];
    const int t = threadIdx.x;
    if (t < 128) {
      float a = 0.f;
      for (int k = 0; k < 128; ++k) a += q_tok[k] * pool_win[t * 128 + k];
      q[t] = a + pool_bin[t];  // q = q_tok@wq.T + bq
    }
    __syncthreads();
    for (int j = t; j < 512; j += 256) {
      const int h = j >> 7, kc = j & 127;
      float a = 0.f;
      for (int d = 0; d < 32; ++d) a += q[32 * h + d] * pool_win[(128 + 32 * h + d) * 128 + kc];
      *(float*)(ws + QK_OFF + 4 * j) = a * 0.17677669529663687f;  // fold 1/sqrt(32); bk dropped (softmax-invariant)
    }
  }
}

// ===================== fused persistent kernel =====================
// 512 blocks x 256 threads; block owns 64 batch rows through the whole net.
// Wave ch owns gate-column j-block [32ch,32ch+32) of all 4 gates -> i,f,g,o in-lane.
__global__ __launch_bounds__(256, 1)
void hfn_main(const float* __restrict__ x14, const float* __restrict__ fa_b,
              const float* __restrict__ pool_bin, const float* __restrict__ pool_bout,
              const float* __restrict__ mu_w, const float* __restrict__ mu_b,
              const float* __restrict__ sig_w, const float* __restrict__ sig_b,
              const float* __restrict__ dmu_w, const float* __restrict__ dmu_b,
              const float* __restrict__ dsig_w, const float* __restrict__ dsig_b,
              char* __restrict__ ws, float* __restrict__ out) {
  __shared__ __align__(16) char smem[163840];  // 160 KiB: wih | x/xw | h
  const int tid = threadIdx.x;
  const int w = tid >> 6;          // wave = gate-column block ch
  const int lane = tid & 63;
  const int l15 = lane & 15, l4 = lane >> 4;
  const int row0 = blockIdx.x << 6;

  int grow[8];  // gate rows this wave's acc tiles cover: 128*G + 32*ch + 16*nt + l15
#pragma unroll
  for (int gq = 0; gq < 8; ++gq) grow[gq] = ((gq >> 1) << 7) + (w << 5) + ((gq & 1) << 4) + l15;

  short8 breg[8][4];               // per-wave B-fragments of whh (enc) / Wd (dec): 128 VGPRs
  float bias_s[8], fbias[8], creg[32], hv[32];

  auto load_breg = [&](int off) {
#pragma unroll
    for (int gq = 0; gq < 8; ++gq)
#pragma unroll
      for (int kk = 0; kk < 4; ++kk)
        breg[gq][kk] = *(const short8*)(ws + off + grow[gq] * 256 + 64 * kk + 16 * l4);
  };
  auto load_x = [&](int t) {       // 64x128 f32 -> bf16 swizzled LDS tile
    const int r = tid >> 2, q = tid & 3;
    const float* src = x14 + ((size_t)(row0 + r) * NDW + t) * 128 + 32 * q;
#pragma unroll
    for (int c = 0; c < 4; ++c) {
      f32x4 v0 = *(const f32x4*)(src + 8 * c);
      f32x4 v1 = *(const f32x4*)(src + 8 * c + 4);
      short8 s;
#pragma unroll
      for (int e = 0; e < 4; ++e) { s[e] = (short)f2bf(v0[e]); s[e + 4] = (short)f2bf(v1[e]); }
      *(short8*)(smem + XOFF + swz(r, 64 * q + 16 * c)) = s;
    }
  };

  // ---- prologue: stage wih (pre-swizzled blob), zero h, load regs, x(t=0) ----
  for (int i = 0; i < 32; ++i) {
    const int off = (tid + (i << 8)) << 4;
    *(f32x4*)(smem + off) = *(const f32x4*)(ws + WIH_OFF + off);
  }
  for (int i = 0; i < 4; ++i) {
    const int off = (tid + (i << 8)) << 4;
    *(f32x4*)(smem + HOFF + off) = splat4(0.f);
  }
  load_breg(WHH_OFF);
#pragma unroll
  for (int gq = 0; gq < 8; ++gq) bias_s[gq] = *(const float*)(ws + EB_OFF + 4 * grow[gq]);
#pragma unroll
  for (int nt = 0; nt < 8; ++nt) fbias[nt] = fa_b[16 * nt + l15];
#pragma unroll
  for (int i = 0; i < 32; ++i) creg[i] = 0.f;
  load_x(0);
  __syncthreads();

  // ======================= encoder: 14 steps =======================
  for (int t = 0; t < NDW; ++t) {
    // S0: spill h_{t-1} history (t-1 in 7..12) + feature attention in place on x tile
    if (t >= 8) {
      char* dst = ws + HH_OFF + ((size_t)blockIdx.x * 6 + (t - 8)) * 16384;
      for (int i = 0; i < 4; ++i) {
        const int off = (tid + (i << 8)) << 4;
        *(f32x4*)(dst + off) = *(const f32x4*)(smem + HOFF + off);
      }
    }
    {
      // wave handles its own 16 rows x all 128 cols -> softmax fully in-wave
      f32x4 patt[8];
#pragma unroll
      for (int nt = 0; nt < 8; ++nt) patt[nt] = splat4(fbias[nt]);
#pragma unroll
      for (int kk = 0; kk < 4; ++kk) {
        const short8 a = *(const short8*)(smem + XOFF + swz(16 * w + l15, 64 * kk + 16 * l4));
#pragma unroll
        for (int nt = 0; nt < 8; ++nt) {
          const short8 b = *(const short8*)(ws + FAW_OFF + (16 * nt + l15) * 256 + 64 * kk + 16 * l4);
          patt[nt] = __builtin_amdgcn_mfma_f32_16x16x32_bf16(a, b, patt[nt], 0, 0, 0);
        }
      }
#pragma unroll
      for (int r = 0; r < 4; ++r) {
        float m = patt[0][r];
#pragma unroll
        for (int nt = 1; nt < 8; ++nt) m = fmaxf(m, patt[nt][r]);
        m = fmaxf(m, __shfl_xor(m, 1)); m = fmaxf(m, __shfl_xor(m, 2));
        m = fmaxf(m, __shfl_xor(m, 4)); m = fmaxf(m, __shfl_xor(m, 8));
        float s = 0.f;
#pragma unroll
        for (int nt = 0; nt < 8; ++nt) { const float e = __expf(patt[nt][r] - m); patt[nt][r] = e; s += e; }
        s += __shfl_xor(s, 1); s += __shfl_xor(s, 2); s += __shfl_xor(s, 4); s += __shfl_xor(s, 8);
        const float rs = __builtin_amdgcn_rcpf(s);
        const int row = 16 * w + 4 * l4 + r;
#pragma unroll
        for (int nt = 0; nt < 8; ++nt) {          // xw = softmax * x, in place (1:1 lane->element)
          const int ad = XOFF + swz(row, 2 * (16 * nt + l15));
          const float xv = bf2f(*(const unsigned short*)(smem + ad));
          *(unsigned short*)(smem + ad) = f2bf(patt[nt][r] * rs * xv);
        }
      }
    }
    __syncthreads();
    // S1: gates = xw@wih.T (LDS B) + h@whh.T (reg B) + bias; LSTM cell in-lane
    {
      f32x4 acc[4][8];
#pragma unroll
      for (int rt = 0; rt < 4; ++rt)
#pragma unroll
        for (int gq = 0; gq < 8; ++gq) acc[rt][gq] = splat4(bias_s[gq]);
#pragma unroll
      for (int kk = 0; kk < 4; ++kk) {
        short8 a[4];
#pragma unroll
        for (int rt = 0; rt < 4; ++rt)
          a[rt] = *(const short8*)(smem + XOFF + swz(16 * rt + l15, 64 * kk + 16 * l4));
#pragma unroll
        for (int gq = 0; gq < 8; ++gq) {
          const short8 b = *(const short8*)(smem + swz(grow[gq], 64 * kk + 16 * l4));
#pragma unroll
          for (int rt = 0; rt < 4; ++rt)
            acc[rt][gq] = __builtin_amdgcn_mfma_f32_16x16x32_bf16(a[rt], b, acc[rt][gq], 0, 0, 0);
        }
      }
#pragma unroll
      for (int kk = 0; kk < 4; ++kk) {
        short8 a[4];
#pragma unroll
        for (int rt = 0; rt < 4; ++rt)
          a[rt] = *(const short8*)(smem + HOFF + swz(16 * rt + l15, 64 * kk + 16 * l4));
#pragma unroll
        for (int gq = 0; gq < 8; ++gq)
#pragma unroll
          for (int rt = 0; rt < 4; ++rt)
            acc[rt][gq] = __builtin_amdgcn_mfma_f32_16x16x32_bf16(a[rt], breg[gq][kk], acc[rt][gq], 0, 0, 0);
      }
#pragma unroll
      for (int rt = 0; rt < 4; ++rt)
#pragma unroll
        for (int nt = 0; nt < 2; ++nt)
#pragma unroll
          for (int r = 0; r < 4; ++r) {
            const int ci = rt * 8 + nt * 4 + r;
            const float iv = acc[rt][0 + nt][r], fv = acc[rt][2 + nt][r];
            const float gv = acc[rt][4 + nt][r], ov = acc[rt][6 + nt][r];
            const float cn = sigmf_(fv) * creg[ci] + sigmf_(iv) * tanhf_(gv);
            creg[ci] = cn;
            hv[ci] = sigmf_(ov) * tanhf_(cn);
          }
    }
    __syncthreads();  // all waves done reading old h / xw
    // S2: write h_t; prefetch x_{t+1}
#pragma unroll
    for (int rt = 0; rt < 4; ++rt)
#pragma unroll
      for (int nt = 0; nt < 2; ++nt)
#pragma unroll
        for (int r = 0; r < 4; ++r) {
          const int row = 16 * rt + 4 * l4 + r;
          const int col = 32 * w + 16 * nt + l15;
          *(unsigned short*)(smem + HOFF + swz(row, 2 * col)) = f2bf(hv[rt * 8 + nt * 4 + r]);
        }
    if (t < NDW - 1) load_x(t + 1);
    __syncthreads();
  }

  // ======================= daily heads (h13) + load pooling history =======================
  {
    const int r = tid >> 2, q = tid & 3;
    float pm = 0.f, ps = 0.f;
#pragma unroll
    for (int c = 0; c < 4; ++c) {
      const short8 h8 = *(const short8*)(smem + HOFF + swz(r, 64 * q + 16 * c));
#pragma unroll
      for (int e = 0; e < 8; ++e) {
        const float hf = bf2f((unsigned short)h8[e]);
        const int k = 32 * q + 8 * c + e;
        pm += hf * mu_w[k];
        ps += hf * sig_w[k];
      }
    }
    pm += __shfl_xor(pm, 1); pm += __shfl_xor(pm, 2);
    ps += __shfl_xor(ps, 1); ps += __shfl_xor(ps, 2);
    if (q == 0) {
      out[row0 + r] = pm + mu_b[0];
      out[B_TOT + row0 + r] = softplusf_(ps + sig_b[0]);
    }
  }
  {  // h_hist (t=7..12) into the now-dead wih region; slot 6 is h13 in HOFF
    const char* src = ws + HH_OFF + (size_t)blockIdx.x * 6 * 16384;
    for (int i = 0; i < 24; ++i) {
      const int off = (tid + (i << 8)) << 4;
      *(f32x4*)(smem + off) = *(const f32x4*)(src + off);
    }
  }
  __syncthreads();

  // ======================= pooling (week0 -> monthly token) =======================
  {  // scores: thread = (row, head); qk already folded+scaled
    const int rw = tid >> 2, hd = tid & 3;
    float sc[7];
#pragma unroll
    for (int s = 0; s < 7; ++s) sc[s] = 0.f;
    const float* qk = (const float*)(ws + QK_OFF) + hd * 128;
#pragma unroll
    for (int kc = 0; kc < 16; ++kc) {
      const f32x4 q0 = *(const f32x4*)(qk + 8 * kc);
      const f32x4 q1 = *(const f32x4*)(qk + 8 * kc + 4);
#pragma unroll
      for (int s = 0; s < 7; ++s) {
        const char* hb = (s < 6) ? (smem + s * 16384) : (smem + HOFF);
        const short8 h8 = *(const short8*)(hb + swz(rw, 16 * kc));
#pragma unroll
        for (int e = 0; e < 4; ++e) {
          sc[s] += bf2f((unsigned short)h8[e]) * q0[e];
          sc[s] += bf2f((unsigned short)h8[e + 4]) * q1[e];
        }
      }
    }
    float m = sc[0];
#pragma unroll
    for (int s = 1; s < 7; ++s) m = fmaxf(m, sc[s]);
    float sum = 0.f;
#pragma unroll
    for (int s = 0; s < 7; ++s) { const float e = __expf(sc[s] - m); sc[s] = e; sum += e; }
    const float rs = __builtin_amdgcn_rcpf(sum);
#pragma unroll
    for (int s = 0; s < 7; ++s)
      *(float*)(smem + SCOFF + ((rw * 4 + hd) * 7 + s) * 4) = sc[s] * rs;
  }
  __syncthreads();
  {  // ctx = sum_s w_s * (h_s @ wv.T); bv folded via sum_s w_s = 1; wave = head
    short8 bv8[2][4];
#pragma unroll
    for (int nt = 0; nt < 2; ++nt)
#pragma unroll
      for (int kk = 0; kk < 4; ++kk)
        bv8[nt][kk] = *(const short8*)(ws + WV_OFF + (32 * w + 16 * nt + l15) * 256 + 64 * kk + 16 * l4);
    f32x4 ctxa[4][2];
#pragma unroll
    for (int nt = 0; nt < 2; ++nt) {
      const float bvv = pool_bin[256 + 32 * w + 16 * nt + l15];
#pragma unroll
      for (int rt = 0; rt < 4; ++rt) ctxa[rt][nt] = splat4(bvv);
    }
    for (int s = 0; s < 7; ++s) {
      const char* hb = (s < 6) ? (smem + s * 16384) : (smem + HOFF);
      f32x4 tmp[4][2];
#pragma unroll
      for (int rt = 0; rt < 4; ++rt)
#pragma unroll
        for (int nt = 0; nt < 2; ++nt) tmp[rt][nt] = splat4(0.f);
#pragma unroll
      for (int kk = 0; kk < 4; ++kk) {
        short8 a[4];
#pragma unroll
        for (int rt = 0; rt < 4; ++rt)
          a[rt] = *(const short8*)(hb + swz(16 * rt + l15, 64 * kk + 16 * l4));
#pragma unroll
        for (int nt = 0; nt < 2; ++nt)
#pragma unroll
          for (int rt = 0; rt < 4; ++rt)
            tmp[rt][nt] = __builtin_amdgcn_mfma_f32_16x16x32_bf16(a[rt], bv8[nt][kk], tmp[rt][nt], 0, 0, 0);
      }
#pragma unroll
      for (int rt = 0; rt < 4; ++rt)
#pragma unroll
        for (int r = 0; r < 4; ++r) {
          const int row = 16 * rt + 4 * l4 + r;
          const float wv = *(const float*)(smem + SCOFF + ((row * 4 + w) * 7 + s) * 4);
#pragma unroll
          for (int nt = 0; nt < 2; ++nt) ctxa[rt][nt][r] += wv * tmp[rt][nt][r];
        }
    }
#pragma unroll
    for (int rt = 0; rt < 4; ++rt)    // ctx -> X tile (bf16) for out-proj GEMM
#pragma unroll
      for (int nt = 0; nt < 2; ++nt)
#pragma unroll
        for (int r = 0; r < 4; ++r) {
          const int row = 16 * rt + 4 * l4 + r;
          const int col = 32 * w + 16 * nt + l15;
          *(unsigned short*)(smem + XOFF + swz(row, 2 * col)) = f2bf(ctxa[rt][nt][r]);
        }
  }
  __syncthreads();
  {  // monthly token = ctx@wout.T + bout -> becomes decoder h0 in HOFF
    short8 bo8[2][4];
#pragma unroll
    for (int nt = 0; nt < 2; ++nt)
#pragma unroll
      for (int kk = 0; kk < 4; ++kk)
        bo8[nt][kk] = *(const short8*)(ws + WOUT_OFF + (32 * w + 16 * nt + l15) * 256 + 64 * kk + 16 * l4);
    f32x4 oa[4][2];
#pragma unroll
    for (int nt = 0; nt < 2; ++nt) {
      const float bo = pool_bout[32 * w + 16 * nt + l15];
#pragma unroll
      for (int rt = 0; rt < 4; ++rt) oa[rt][nt] = splat4(bo);
    }
#pragma unroll
    for (int kk = 0; kk < 4; ++kk) {
      short8 a[4];
#pragma unroll
      for (int rt = 0; rt < 4; ++rt)
        a[rt] = *(const short8*)(smem + XOFF + swz(16 * rt + l15, 64 * kk + 16 * l4));
#pragma unroll
      for (int nt = 0; nt < 2; ++nt)
#pragma unroll
        for (int rt = 0; rt < 4; ++rt)
          oa[rt][nt] = __builtin_amdgcn_mfma_f32_16x16x32_bf16(a[rt], bo8[nt][kk], oa[rt][nt], 0, 0, 0);
    }
#pragma unroll
    for (int rt = 0; rt < 4; ++rt)
#pragma unroll
      for (int nt = 0; nt < 2; ++nt)
#pragma unroll
        for (int r = 0; r < 4; ++r) {
          const int row = 16 * rt + 4 * l4 + r;
          const int col = 32 * w + 16 * nt + l15;
          *(unsigned short*)(smem + HOFF + swz(row, 2 * col)) = f2bf(oa[rt][nt][r]);
        }
  }
  __syncthreads();

  // ======================= decoder: 30 steps =======================
#pragma unroll
  for (int gq = 0; gq < 8; ++gq) bias_s[gq] = *(const float*)(ws + DB_OFF + 4 * grow[gq]);
  load_breg(DWHH_OFF);  // step 0: x=0 -> gates = tok@dwhh.T + bias
#pragma unroll
  for (int i = 0; i < 32; ++i) creg[i] = 0.f;
  for (int t = 0; t < NSTEPS; ++t) {
    {
      f32x4 acc[4][8];
#pragma unroll
      for (int rt = 0; rt < 4; ++rt)
#pragma unroll
        for (int gq = 0; gq < 8; ++gq) acc[rt][gq] = splat4(bias_s[gq]);
#pragma unroll
      for (int kk = 0; kk < 4; ++kk) {
        short8 a[4];
#pragma unroll
        for (int rt = 0; rt < 4; ++rt)
          a[rt] = *(const short8*)(smem + HOFF + swz(16 * rt + l15, 64 * kk + 16 * l4));
#pragma unroll
        for (int gq = 0; gq < 8; ++gq)
#pragma unroll
          for (int rt = 0; rt < 4; ++rt)
            acc[rt][gq] = __builtin_amdgcn_mfma_f32_16x16x32_bf16(a[rt], breg[gq][kk], acc[rt][gq], 0, 0, 0);
      }
#pragma unroll
      for (int rt = 0; rt < 4; ++rt)
#pragma unroll
        for (int nt = 0; nt < 2; ++nt)
#pragma unroll
          for (int r = 0; r < 4; ++r) {
            const int ci = rt * 8 + nt * 4 + r;
            const float iv = acc[rt][0 + nt][r], fv = acc[rt][2 + nt][r];
            const float gv = acc[rt][4 + nt][r], ov = acc[rt][6 + nt][r];
            const float cn = sigmf_(fv) * creg[ci] + sigmf_(iv) * tanhf_(gv);
            creg[ci] = cn;
            hv[ci] = sigmf_(ov) * tanhf_(cn);
          }
    }
    __syncthreads();  // all h reads done
#pragma unroll
    for (int rt = 0; rt < 4; ++rt)
#pragma unroll
      for (int nt = 0; nt < 2; ++nt)
#pragma unroll
        for (int r = 0; r < 4; ++r) {
          const int row = 16 * rt + 4 * l4 + r;
          const int col = 32 * w + 16 * nt + l15;
          *(unsigned short*)(smem + HOFF + swz(row, 2 * col)) = f2bf(hv[rt * 8 + nt * 4 + r]);
        }
    if (t == 0) load_breg(WD_OFF);  // x_t == h_t for t>=1: combined weights
    __syncthreads();
    {  // monthly heads from new h
      const int r = tid >> 2, q = tid & 3;
      float pm = 0.f, ps = 0.f;
#pragma unroll
      for (int c = 0; c < 4; ++c) {
        const short8 h8 = *(const short8*)(smem + HOFF + swz(r, 64 * q + 16 * c));
#pragma unroll
        for (int e = 0; e < 8; ++e) {
          const float hf = bf2f((unsigned short)h8[e]);
          const int k = 32 * q + 8 * c + e;
          pm += hf * dmu_w[k];
          ps += hf * dsig_w[k];
        }
      }
      pm += __shfl_xor(pm, 1); pm += __shfl_xor(pm, 2);
      ps += __shfl_xor(ps, 1); ps += __shfl_xor(ps, 2);
      if (q == 0) {
        out[2 * B_TOT + (size_t)(row0 + r) * 30 + t] = pm + dmu_b[0];
        out[32 * B_TOT + (size_t)(row0 + r) * 30 + t] = softplusf_(ps + dsig_b[0]);
      }
    }
  }
}

extern "C" void kernel_launch(void* const* d_in, const int* in_sizes, int n_in,
                              void* d_out, int out_size, void* d_ws, size_t ws_size,
                              hipStream_t stream) {
  (void)in_sizes; (void)n_in; (void)out_size; (void)ws_size;  // requires ws_size >= ~51 MB
  const float* x14      = (const float*)d_in[0];
  const float* fa_w     = (const float*)d_in[1];
  const float* fa_b     = (const float*)d_in[2];
  const float* enc_wih  = (const float*)d_in[3];
  const float* enc_whh  = (const float*)d_in[4];
  const float* enc_bih  = (const float*)d_in[5];
  const float* enc_bhh  = (const float*)d_in[6];
  const float* q_tok    = (const float*)d_in[7];
  const float* pool_win = (const float*)d_in[8];
  const float* pool_bin = (const float*)d_in[9];
  const float* pool_wout= (const float*)d_in[10];
  const float* pool_bout= (const float*)d_in[11];
  const float* mu_w     = (const float*)d_in[12];
  const float* mu_b     = (const float*)d_in[13];
  const float* sig_w    = (const float*)d_in[14];
  const float* sig_b    = (const float*)d_in[15];
  const float* dec_wih  = (const float*)d_in[16];
  const float* dec_whh  = (const float*)d_in[17];
  const float* dec_bih  = (const float*)d_in[18];
  const float* dec_bhh  = (const float*)d_in[19];
  const float* dmu_w    = (const float*)d_in[20];
  const float* dmu_b    = (const float*)d_in[21];
  const float* dsig_w   = (const float*)d_in[22];
  const float* dsig_b   = (const float*)d_in[23];
  char* ws = (char*)d_ws;

  hfn_prep<<<dim3(128), dim3(256), 0, stream>>>(fa_w, enc_wih, enc_whh, enc_bih, enc_bhh,
      q_tok, pool_win, pool_bin, pool_wout, dec_wih, dec_whh, dec_bih, dec_bhh, ws);
  hfn_main<<<dim3(512), dim3(256), 0, stream>>>(x14, fa_b, pool_bin, pool_bout,
      mu_w, mu_b, sig_w, sig_b, dmu_w, dmu_b, dsig_w, dsig_b, ws, (float*)d_out);
}

// Round 2
// 667.929 us; speedup vs baseline: 1.9456x; 1.9456x over previous
//
#include <hip/hip_runtime.h>

#define B_TOT 32768
#define NDW 14
#define NSTEPS 30

typedef __attribute__((ext_vector_type(8))) short short8;
typedef __attribute__((ext_vector_type(4))) float f32x4;

// ---- workspace byte offsets ----
#define WIH_OFF   0           // enc_wih bf16 plain [512][128]
#define WHH_OFF   131072      // enc_whh bf16 plain [512][128]
#define WD_OFF    262144      // dec_wih+dec_whh bf16 plain [512][128]
#define DWHH_OFF  393216      // dec_whh bf16 plain [512][128]
#define FAW_OFF   524288      // fa_w bf16 plain [128][128]
#define WV_OFF    557056      // pooling wv bf16 plain [128][128]
#define WOUT_OFF  589824      // pool_wout bf16 plain [128][128]
#define QK_OFF    622592      // folded q@wk / sqrt(dh), f32 [4][128]
#define EB_OFF    624640      // enc_bih+enc_bhh f32 [512]
#define DB_OFF    626688      // dec_bih+dec_bhh f32 [512]
#define XW_OFF    628736      // precomputed xw, swizzled bf16 tiles [512*14][16384 B]
#define XW_NEED   (628736ULL + 7168ULL * 16384ULL)   // ~118 MB

// ---- LDS byte offsets (160 KiB exactly): hist[6] | XW[2] | H[2] ----
#define LXW   98304    // 2 x 16K xw / x staging buffers (reused: ctx tile, scores)
#define LH    131072   // 2 x 16K h buffers
#define LSC   114688   // pooling scores f32 [64][4][7] (= LXW buffer 1)

__device__ __forceinline__ unsigned short f2bf(float f) {
  unsigned int u = __float_as_uint(f);
  u += 0x7fffu + ((u >> 16) & 1u);
  return (unsigned short)(u >> 16);
}
__device__ __forceinline__ float bf2f(unsigned short h) {
  return __uint_as_float(((unsigned int)h) << 16);
}
__device__ __forceinline__ float sigmf_(float x) { return __builtin_amdgcn_rcpf(1.f + __expf(-x)); }
__device__ __forceinline__ float tanhf_(float x) { return 1.f - 2.f * __builtin_amdgcn_rcpf(1.f + __expf(2.f * x)); }
__device__ __forceinline__ float softplusf_(float x) { return x > 20.f ? x : __logf(1.f + __expf(x)); }
__device__ __forceinline__ int swz(int row, int bc) { return row * 256 + (bc ^ ((row & 7) << 4)); }
__device__ __forceinline__ f32x4 splat4(float v) { f32x4 r = {v, v, v, v}; return r; }

// ===================== prep: weight conversion / folding =====================
__global__ void hfn_prep(const float* __restrict__ fa_w,
                         const float* __restrict__ enc_wih, const float* __restrict__ enc_whh,
                         const float* __restrict__ enc_bih, const float* __restrict__ enc_bhh,
                         const float* __restrict__ q_tok,
                         const float* __restrict__ pool_win, const float* __restrict__ pool_bin,
                         const float* __restrict__ pool_wout,
                         const float* __restrict__ dec_wih, const float* __restrict__ dec_whh,
                         const float* __restrict__ dec_bih, const float* __restrict__ dec_bhh,
                         char* __restrict__ ws) {
  const int gt = blockIdx.x * 256 + threadIdx.x;
  const int gs = gridDim.x * 256;
  for (int i = gt; i < 65536; i += gs) *(unsigned short*)(ws + WIH_OFF + 2 * i) = f2bf(enc_wih[i]);
  for (int i = gt; i < 65536; i += gs) *(unsigned short*)(ws + WHH_OFF + 2 * i) = f2bf(enc_whh[i]);
  for (int i = gt; i < 65536; i += gs) *(unsigned short*)(ws + WD_OFF + 2 * i) = f2bf(dec_wih[i] + dec_whh[i]);
  for (int i = gt; i < 65536; i += gs) *(unsigned short*)(ws + DWHH_OFF + 2 * i) = f2bf(dec_whh[i]);
  for (int i = gt; i < 16384; i += gs) *(unsigned short*)(ws + FAW_OFF + 2 * i) = f2bf(fa_w[i]);
  for (int i = gt; i < 16384; i += gs) *(unsigned short*)(ws + WV_OFF + 2 * i) = f2bf(pool_win[32768 + i]);
  for (int i = gt; i < 16384; i += gs) *(unsigned short*)(ws + WOUT_OFF + 2 * i) = f2bf(pool_wout[i]);
  for (int i = gt; i < 512; i += gs) *(float*)(ws + EB_OFF + 4 * i) = enc_bih[i] + enc_bhh[i];
  for (int i = gt; i < 512; i += gs) *(float*)(ws + DB_OFF + 4 * i) = dec_bih[i] + dec_bhh[i];
  if (blockIdx.x == 0) {
    __shared__ float q[128];
    const int t = threadIdx.x;
    if (t < 128) {
      float a = 0.f;
      for (int k = 0; k < 128; ++k) a += q_tok[k] * pool_win[t * 128 + k];
      q[t] = a + pool_bin[t];
    }
    __syncthreads();
    for (int j = t; j < 512; j += 256) {
      const int h = j >> 7, kc = j & 127;
      float a = 0.f;
      for (int d = 0; d < 32; ++d) a += q[32 * h + d] * pool_win[(128 + 32 * h + d) * 128 + kc];
      *(float*)(ws + QK_OFF + 4 * j) = a * 0.17677669529663687f;  // bk dropped (softmax-invariant)
    }
  }
}

// ===================== pre-pass: feature attention for all (b,t) =====================
// grid 512*14 blocks x 256 threads; block = (mb, t); writes swizzled bf16 xw tile to ws.
__global__ __launch_bounds__(256) void hfn_attn(const float* __restrict__ x14,
                                                const float* __restrict__ fa_b,
                                                char* __restrict__ ws) {
  __shared__ __align__(16) char sx[16384];
  const int tid = threadIdx.x;
  const int w = tid >> 6, lane = tid & 63, l15 = lane & 15, l4 = lane >> 4;
  const int bx = blockIdx.x;
  const int mb = bx / 14, t = bx - mb * 14;
  const int row0 = mb << 6;
  {  // load x tile f32 -> bf16 swizzled
    const int r = tid >> 2, q = tid & 3;
    const float* src = x14 + ((size_t)(row0 + r) * NDW + t) * 128 + 32 * q;
#pragma unroll
    for (int c = 0; c < 4; ++c) {
      f32x4 v0 = *(const f32x4*)(src + 8 * c);
      f32x4 v1 = *(const f32x4*)(src + 8 * c + 4);
      short8 s;
#pragma unroll
      for (int e = 0; e < 4; ++e) { s[e] = (short)f2bf(v0[e]); s[e + 4] = (short)f2bf(v1[e]); }
      *(short8*)(sx + swz(r, 64 * q + 16 * c)) = s;
    }
  }
  __syncthreads();
  {  // attention: wave handles 16 rows
    float fbias[8];
#pragma unroll
    for (int nt = 0; nt < 8; ++nt) fbias[nt] = fa_b[16 * nt + l15];
    f32x4 patt[8];
#pragma unroll
    for (int nt = 0; nt < 8; ++nt) patt[nt] = splat4(fbias[nt]);
#pragma unroll
    for (int kk = 0; kk < 4; ++kk) {
      const short8 a = *(const short8*)(sx + swz(16 * w + l15, 64 * kk + 16 * l4));
#pragma unroll
      for (int nt = 0; nt < 8; ++nt) {
        const short8 b = *(const short8*)(ws + FAW_OFF + (16 * nt + l15) * 256 + 64 * kk + 16 * l4);
        patt[nt] = __builtin_amdgcn_mfma_f32_16x16x32_bf16(a, b, patt[nt], 0, 0, 0);
      }
    }
#pragma unroll
    for (int r = 0; r < 4; ++r) {
      float m = patt[0][r];
#pragma unroll
      for (int nt = 1; nt < 8; ++nt) m = fmaxf(m, patt[nt][r]);
      m = fmaxf(m, __shfl_xor(m, 1)); m = fmaxf(m, __shfl_xor(m, 2));
      m = fmaxf(m, __shfl_xor(m, 4)); m = fmaxf(m, __shfl_xor(m, 8));
      float s = 0.f;
#pragma unroll
      for (int nt = 0; nt < 8; ++nt) { const float e = __expf(patt[nt][r] - m); patt[nt][r] = e; s += e; }
      s += __shfl_xor(s, 1); s += __shfl_xor(s, 2); s += __shfl_xor(s, 4); s += __shfl_xor(s, 8);
      const float rs = __builtin_amdgcn_rcpf(s);
      const int row = 16 * w + 4 * l4 + r;
#pragma unroll
      for (int nt = 0; nt < 8; ++nt) {
        const int ad = swz(row, 2 * (16 * nt + l15));
        const float xv = bf2f(*(const unsigned short*)(sx + ad));
        *(unsigned short*)(sx + ad) = f2bf(patt[nt][r] * rs * xv);
      }
    }
  }
  __syncthreads();
  {  // copy swizzled tile to ws blob
    char* dst = ws + XW_OFF + (size_t)bx * 16384;
#pragma unroll
    for (int i = 0; i < 4; ++i) {
      const int off = (tid + 256 * i) << 4;
      *(f32x4*)(dst + off) = *(const f32x4*)(sx + off);
    }
  }
}

// ===================== fused persistent kernel =====================
// 512 blocks x 512 threads (8 waves); block owns 64 rows; wave w owns gate-cols [16w,16w+16).
// MODE 0: xw precomputed in ws.  MODE 1: inline attention fallback (small ws).
template<int MODE>
__global__ __launch_bounds__(512, 2)
void hfn_main(const float* __restrict__ x14, const float* __restrict__ fa_b,
              const float* __restrict__ pool_bin, const float* __restrict__ pool_bout,
              const float* __restrict__ mu_w, const float* __restrict__ mu_b,
              const float* __restrict__ sig_w, const float* __restrict__ sig_b,
              const float* __restrict__ dmu_w, const float* __restrict__ dmu_b,
              const float* __restrict__ dsig_w, const float* __restrict__ dsig_b,
              char* __restrict__ ws, float* __restrict__ out) {
  __shared__ __align__(16) char smem[163840];
  const int tid = threadIdx.x;
  const int w = tid >> 6, lane = tid & 63, l15 = lane & 15, l4 = lane >> 4;
  const int row0 = blockIdx.x << 6;

  int grow[4];
#pragma unroll
  for (int g = 0; g < 4; ++g) grow[g] = (g << 7) + (w << 4) + l15;

  short8 bih[4][4], bhh[4][4];
  float bias_s[4], creg[16], fbias[8];
  f32x4 xs0, xs1;

  auto load_bhh = [&](int off) {
#pragma unroll
    for (int g = 0; g < 4; ++g)
#pragma unroll
      for (int kk = 0; kk < 4; ++kk)
        bhh[g][kk] = *(const short8*)(ws + off + grow[g] * 256 + 64 * kk + 16 * l4);
  };
  auto load_x512 = [&](int t, char* dst) {  // MODE 1: stage x tile f32->bf16 swizzled
    const int r = tid >> 3, q = tid & 7;
    const float* src = x14 + ((size_t)(row0 + r) * NDW + t) * 128 + 16 * q;
    f32x4 v0 = *(const f32x4*)(src),     v1 = *(const f32x4*)(src + 4);
    f32x4 v2 = *(const f32x4*)(src + 8), v3 = *(const f32x4*)(src + 12);
    short8 s0, s1;
#pragma unroll
    for (int e = 0; e < 4; ++e) {
      s0[e] = (short)f2bf(v0[e]); s0[e + 4] = (short)f2bf(v1[e]);
      s1[e] = (short)f2bf(v2[e]); s1[e + 4] = (short)f2bf(v3[e]);
    }
    *(short8*)(dst + swz(r, 32 * q)) = s0;
    *(short8*)(dst + swz(r, 32 * q + 16)) = s1;
  };

  // ---- prologue ----
#pragma unroll
  for (int g = 0; g < 4; ++g)
#pragma unroll
    for (int kk = 0; kk < 4; ++kk)
      bih[g][kk] = *(const short8*)(ws + WIH_OFF + grow[g] * 256 + 64 * kk + 16 * l4);
  load_bhh(WHH_OFF);
#pragma unroll
  for (int g = 0; g < 4; ++g) bias_s[g] = *(const float*)(ws + EB_OFF + 4 * grow[g]);
#pragma unroll
  for (int i = 0; i < 16; ++i) creg[i] = 0.f;
  *(f32x4*)(smem + LH + tid * 32) = splat4(0.f);        // h_{-1} = 0 in H[0]
  *(f32x4*)(smem + LH + tid * 32 + 16) = splat4(0.f);
  if (MODE == 0) {
    const char* src = ws + XW_OFF + (size_t)(blockIdx.x * 14) * 16384 + tid * 32;
    xs0 = *(const f32x4*)src; xs1 = *(const f32x4*)(src + 16);
    *(f32x4*)(smem + LXW + tid * 32) = xs0;
    *(f32x4*)(smem + LXW + tid * 32 + 16) = xs1;
  } else {
#pragma unroll
    for (int nt = 0; nt < 8; ++nt) fbias[nt] = fa_b[16 * nt + l15];
    load_x512(0, smem + LXW);
  }
  __syncthreads();

  // ======================= encoder: 14 steps, 1 barrier/step (MODE 0) =======================
  for (int t = 0; t < NDW; ++t) {
    const int rb = t & 1;
    char* XWr = smem + LXW + rb * 16384;
    char* Hr  = smem + LH + rb * 16384;
    char* Hw  = smem + LH + (rb ^ 1) * 16384;
    if (t >= 8) {  // copy h_{t-1} (t-1 in 7..12) -> hist slot t-8 (LDS->LDS)
      char* hdst = smem + (t - 8) * 16384;
      *(f32x4*)(hdst + tid * 32) = *(const f32x4*)(Hr + tid * 32);
      *(f32x4*)(hdst + tid * 32 + 16) = *(const f32x4*)(Hr + tid * 32 + 16);
    }
    if (MODE == 0) {
      if (t < NDW - 1) {  // issue next xw tile load early (hides under compute)
        const char* src = ws + XW_OFF + (size_t)(blockIdx.x * 14 + t + 1) * 16384 + tid * 32;
        xs0 = *(const f32x4*)src; xs1 = *(const f32x4*)(src + 16);
      }
    } else {
      if (w < 4) {  // inline attention on XWr (wave-uniform branch; waves 4-7 wait)
        f32x4 patt[8];
#pragma unroll
        for (int nt = 0; nt < 8; ++nt) patt[nt] = splat4(fbias[nt]);
#pragma unroll
        for (int kk = 0; kk < 4; ++kk) {
          const short8 a = *(const short8*)(XWr + swz(16 * w + l15, 64 * kk + 16 * l4));
#pragma unroll
          for (int nt = 0; nt < 8; ++nt) {
            const short8 b = *(const short8*)(ws + FAW_OFF + (16 * nt + l15) * 256 + 64 * kk + 16 * l4);
            patt[nt] = __builtin_amdgcn_mfma_f32_16x16x32_bf16(a, b, patt[nt], 0, 0, 0);
          }
        }
#pragma unroll
        for (int r = 0; r < 4; ++r) {
          float m = patt[0][r];
#pragma unroll
          for (int nt = 1; nt < 8; ++nt) m = fmaxf(m, patt[nt][r]);
          m = fmaxf(m, __shfl_xor(m, 1)); m = fmaxf(m, __shfl_xor(m, 2));
          m = fmaxf(m, __shfl_xor(m, 4)); m = fmaxf(m, __shfl_xor(m, 8));
          float s = 0.f;
#pragma unroll
          for (int nt = 0; nt < 8; ++nt) { const float e = __expf(patt[nt][r] - m); patt[nt][r] = e; s += e; }
          s += __shfl_xor(s, 1); s += __shfl_xor(s, 2); s += __shfl_xor(s, 4); s += __shfl_xor(s, 8);
          const float rs = __builtin_amdgcn_rcpf(s);
          const int row = 16 * w + 4 * l4 + r;
#pragma unroll
          for (int nt = 0; nt < 8; ++nt) {
            const int ad = swz(row, 2 * (16 * nt + l15));
            const float xv = bf2f(*(const unsigned short*)(XWr + ad));
            *(unsigned short*)(XWr + ad) = f2bf(patt[nt][r] * rs * xv);
          }
        }
      }
      __syncthreads();
    }
    // gates = xw@wih.T + h@whh.T + bias (all B-frags in registers)
    {
      f32x4 acc[4][4];
#pragma unroll
      for (int rt = 0; rt < 4; ++rt)
#pragma unroll
        for (int g = 0; g < 4; ++g) acc[rt][g] = splat4(bias_s[g]);
#pragma unroll
      for (int kk = 0; kk < 4; ++kk) {
        short8 a[4];
#pragma unroll
        for (int rt = 0; rt < 4; ++rt)
          a[rt] = *(const short8*)(XWr + swz(16 * rt + l15, 64 * kk + 16 * l4));
#pragma unroll
        for (int g = 0; g < 4; ++g)
#pragma unroll
          for (int rt = 0; rt < 4; ++rt)
            acc[rt][g] = __builtin_amdgcn_mfma_f32_16x16x32_bf16(a[rt], bih[g][kk], acc[rt][g], 0, 0, 0);
      }
#pragma unroll
      for (int kk = 0; kk < 4; ++kk) {
        short8 a[4];
#pragma unroll
        for (int rt = 0; rt < 4; ++rt)
          a[rt] = *(const short8*)(Hr + swz(16 * rt + l15, 64 * kk + 16 * l4));
#pragma unroll
        for (int g = 0; g < 4; ++g)
#pragma unroll
          for (int rt = 0; rt < 4; ++rt)
            acc[rt][g] = __builtin_amdgcn_mfma_f32_16x16x32_bf16(a[rt], bhh[g][kk], acc[rt][g], 0, 0, 0);
      }
#pragma unroll
      for (int rt = 0; rt < 4; ++rt)
#pragma unroll
        for (int r = 0; r < 4; ++r) {
          const int ci = rt * 4 + r;
          const float iv = acc[rt][0][r], fv = acc[rt][1][r];
          const float gv = acc[rt][2][r], ov = acc[rt][3][r];
          const float cn = sigmf_(fv) * creg[ci] + sigmf_(iv) * tanhf_(gv);
          creg[ci] = cn;
          const int row = 16 * rt + 4 * l4 + r;
          *(unsigned short*)(Hw + swz(row, 2 * (16 * w + l15))) = f2bf(sigmf_(ov) * tanhf_(cn));
        }
    }
    if (t < NDW - 1) {
      char* XWn = smem + LXW + (rb ^ 1) * 16384;
      if (MODE == 0) {
        *(f32x4*)(XWn + tid * 32) = xs0;
        *(f32x4*)(XWn + tid * 32 + 16) = xs1;
      } else {
        load_x512(t + 1, XWn);
      }
    }
    __syncthreads();
  }
  // h13 now in H[0] (t=13 wrote rb^1 = 0)

  // ======================= daily heads + pooling scores (read-only phase) =======================
  {
    const int r = tid >> 3, q = tid & 7;
    const short8 h8a = *(const short8*)(smem + LH + swz(r, 32 * q));
    const short8 h8b = *(const short8*)(smem + LH + swz(r, 32 * q + 16));
    float pm = 0.f, ps = 0.f;
#pragma unroll
    for (int e = 0; e < 8; ++e) {
      const float ha = bf2f((unsigned short)h8a[e]), hb = bf2f((unsigned short)h8b[e]);
      pm += ha * mu_w[16 * q + e] + hb * mu_w[16 * q + 8 + e];
      ps += ha * sig_w[16 * q + e] + hb * sig_w[16 * q + 8 + e];
    }
    pm += __shfl_xor(pm, 1); pm += __shfl_xor(pm, 2); pm += __shfl_xor(pm, 4);
    ps += __shfl_xor(ps, 1); ps += __shfl_xor(ps, 2); ps += __shfl_xor(ps, 4);
    if (q == 0) {
      out[row0 + r] = pm + mu_b[0];
      out[B_TOT + row0 + r] = softplusf_(ps + sig_b[0]);
    }
  }
  {  // scores: thread = (row, head, k-half); hist slots 0-5 + h13 (H[0])
    const int rw = tid >> 3, hd = (tid >> 1) & 3, kh = tid & 1;
    float sc[7];
#pragma unroll
    for (int s = 0; s < 7; ++s) sc[s] = 0.f;
    const float* qk = (const float*)(ws + QK_OFF) + hd * 128 + kh * 64;
#pragma unroll
    for (int kc = 0; kc < 8; ++kc) {
      const int kca = 8 * kh + kc;
      const f32x4 q0 = *(const f32x4*)(qk + 8 * kc);
      const f32x4 q1 = *(const f32x4*)(qk + 8 * kc + 4);
#pragma unroll
      for (int s = 0; s < 7; ++s) {
        const char* hb = (s < 6) ? (smem + s * 16384) : (smem + LH);
        const short8 h8 = *(const short8*)(hb + swz(rw, 16 * kca));
#pragma unroll
        for (int e = 0; e < 4; ++e)
          sc[s] += bf2f((unsigned short)h8[e]) * q0[e] + bf2f((unsigned short)h8[e + 4]) * q1[e];
      }
    }
#pragma unroll
    for (int s = 0; s < 7; ++s) sc[s] += __shfl_xor(sc[s], 1);
    if (kh == 0) {
      float m = sc[0];
#pragma unroll
      for (int s = 1; s < 7; ++s) m = fmaxf(m, sc[s]);
      float sum = 0.f;
#pragma unroll
      for (int s = 0; s < 7; ++s) { const float e = __expf(sc[s] - m); sc[s] = e; sum += e; }
      const float rs = __builtin_amdgcn_rcpf(sum);
#pragma unroll
      for (int s = 0; s < 7; ++s)
        *(float*)(smem + LSC + ((rw * 4 + hd) * 7 + s) * 4) = sc[s] * rs;
    }
  }
  __syncthreads();

  // ======================= pooling ctx (waves 0-3, wave = head) =======================
  if (w < 4) {
    short8 bv8[2][4];
#pragma unroll
    for (int nt = 0; nt < 2; ++nt)
#pragma unroll
      for (int kk = 0; kk < 4; ++kk)
        bv8[nt][kk] = *(const short8*)(ws + WV_OFF + (32 * w + 16 * nt + l15) * 256 + 64 * kk + 16 * l4);
    f32x4 ctxa[4][2];
#pragma unroll
    for (int nt = 0; nt < 2; ++nt) {
      const float bvv = pool_bin[256 + 32 * w + 16 * nt + l15];
#pragma unroll
      for (int rt = 0; rt < 4; ++rt) ctxa[rt][nt] = splat4(bvv);
    }
    for (int s = 0; s < 7; ++s) {
      const char* hb = (s < 6) ? (smem + s * 16384) : (smem + LH);
      f32x4 tmp[4][2];
#pragma unroll
      for (int rt = 0; rt < 4; ++rt)
#pragma unroll
        for (int nt = 0; nt < 2; ++nt) tmp[rt][nt] = splat4(0.f);
#pragma unroll
      for (int kk = 0; kk < 4; ++kk) {
        short8 a[4];
#pragma unroll
        for (int rt = 0; rt < 4; ++rt)
          a[rt] = *(const short8*)(hb + swz(16 * rt + l15, 64 * kk + 16 * l4));
#pragma unroll
        for (int nt = 0; nt < 2; ++nt)
#pragma unroll
          for (int rt = 0; rt < 4; ++rt)
            tmp[rt][nt] = __builtin_amdgcn_mfma_f32_16x16x32_bf16(a[rt], bv8[nt][kk], tmp[rt][nt], 0, 0, 0);
      }
#pragma unroll
      for (int rt = 0; rt < 4; ++rt)
#pragma unroll
        for (int r = 0; r < 4; ++r) {
          const int row = 16 * rt + 4 * l4 + r;
          const float wv = *(const float*)(smem + LSC + ((row * 4 + w) * 7 + s) * 4);
#pragma unroll
          for (int nt = 0; nt < 2; ++nt) ctxa[rt][nt][r] += wv * tmp[rt][nt][r];
        }
    }
#pragma unroll
    for (int rt = 0; rt < 4; ++rt)
#pragma unroll
      for (int nt = 0; nt < 2; ++nt)
#pragma unroll
        for (int r = 0; r < 4; ++r) {
          const int row = 16 * rt + 4 * l4 + r;
          *(unsigned short*)(smem + LXW + swz(row, 2 * (32 * w + 16 * nt + l15))) = f2bf(ctxa[rt][nt][r]);
        }
  }
  __syncthreads();
  // out-proj (waves 0-3) -> token in H[1]; waves 4-7 stage decoder head weights into slot 0
  if (w < 4) {
    short8 bo8[2][4];
#pragma unroll
    for (int nt = 0; nt < 2; ++nt)
#pragma unroll
      for (int kk = 0; kk < 4; ++kk)
        bo8[nt][kk] = *(const short8*)(ws + WOUT_OFF + (32 * w + 16 * nt + l15) * 256 + 64 * kk + 16 * l4);
    f32x4 oa[4][2];
#pragma unroll
    for (int nt = 0; nt < 2; ++nt) {
      const float bo = pool_bout[32 * w + 16 * nt + l15];
#pragma unroll
      for (int rt = 0; rt < 4; ++rt) oa[rt][nt] = splat4(bo);
    }
#pragma unroll
    for (int kk = 0; kk < 4; ++kk) {
      short8 a[4];
#pragma unroll
      for (int rt = 0; rt < 4; ++rt)
        a[rt] = *(const short8*)(smem + LXW + swz(16 * rt + l15, 64 * kk + 16 * l4));
#pragma unroll
      for (int nt = 0; nt < 2; ++nt)
#pragma unroll
        for (int rt = 0; rt < 4; ++rt)
          oa[rt][nt] = __builtin_amdgcn_mfma_f32_16x16x32_bf16(a[rt], bo8[nt][kk], oa[rt][nt], 0, 0, 0);
    }
#pragma unroll
    for (int rt = 0; rt < 4; ++rt)
#pragma unroll
      for (int nt = 0; nt < 2; ++nt)
#pragma unroll
        for (int r = 0; r < 4; ++r) {
          const int row = 16 * rt + 4 * l4 + r;
          *(unsigned short*)(smem + LH + 16384 + swz(row, 2 * (32 * w + 16 * nt + l15))) = f2bf(oa[rt][nt][r]);
        }
  } else {
    const int tt = tid - 256;
    if (tt < 128) ((float*)smem)[tt] = dmu_w[tt];
    else ((float*)smem)[tt] = dsig_w[tt - 128];
  }
  __syncthreads();

  // ======================= decoder: 30 steps, 1 barrier/step =======================
#pragma unroll
  for (int g = 0; g < 4; ++g) bias_s[g] = *(const float*)(ws + DB_OFF + 4 * grow[g]);
  load_bhh(DWHH_OFF);  // t=0: x=0 -> gates = tok@dwhh.T + bias
#pragma unroll
  for (int i = 0; i < 16; ++i) creg[i] = 0.f;
  const float dmub = dmu_b[0], dsigb = dsig_b[0];
  for (int t = 0; t < NSTEPS; ++t) {
    char* Hr = smem + LH + ((t + 1) & 1) * 16384;   // t=0 -> H[1] (token)
    char* Hw = smem + LH + (t & 1) * 16384;
    {
      f32x4 acc[4][4];
#pragma unroll
      for (int rt = 0; rt < 4; ++rt)
#pragma unroll
        for (int g = 0; g < 4; ++g) acc[rt][g] = splat4(bias_s[g]);
#pragma unroll
      for (int kk = 0; kk < 4; ++kk) {
        short8 a[4];
#pragma unroll
        for (int rt = 0; rt < 4; ++rt)
          a[rt] = *(const short8*)(Hr + swz(16 * rt + l15, 64 * kk + 16 * l4));
#pragma unroll
        for (int g = 0; g < 4; ++g)
#pragma unroll
          for (int rt = 0; rt < 4; ++rt)
            acc[rt][g] = __builtin_amdgcn_mfma_f32_16x16x32_bf16(a[rt], bhh[g][kk], acc[rt][g], 0, 0, 0);
      }
#pragma unroll
      for (int rt = 0; rt < 4; ++rt)
#pragma unroll
        for (int r = 0; r < 4; ++r) {
          const int ci = rt * 4 + r;
          const float iv = acc[rt][0][r], fv = acc[rt][1][r];
          const float gv = acc[rt][2][r], ov = acc[rt][3][r];
          const float cn = sigmf_(fv) * creg[ci] + sigmf_(iv) * tanhf_(gv);
          creg[ci] = cn;
          const int row = 16 * rt + 4 * l4 + r;
          *(unsigned short*)(Hw + swz(row, 2 * (16 * w + l15))) = f2bf(sigmf_(ov) * tanhf_(cn));
        }
    }
    if (t == 0) load_bhh(WD_OFF);  // x_t == h_t for t>=1: combined weights
    __syncthreads();
    {  // monthly heads from new h (head weights in LDS slot 0)
      const int r = tid >> 3, q = tid & 7;
      const short8 h8a = *(const short8*)(Hw + swz(r, 32 * q));
      const short8 h8b = *(const short8*)(Hw + swz(r, 32 * q + 16));
      const float* dmuS = (const float*)smem;
      float pm = 0.f, ps = 0.f;
#pragma unroll
      for (int e = 0; e < 8; ++e) {
        const float ha = bf2f((unsigned short)h8a[e]), hb = bf2f((unsigned short)h8b[e]);
        pm += ha * dmuS[16 * q + e] + hb * dmuS[16 * q + 8 + e];
        ps += ha * dmuS[128 + 16 * q + e] + hb * dmuS[128 + 16 * q + 8 + e];
      }
      pm += __shfl_xor(pm, 1); pm += __shfl_xor(pm, 2); pm += __shfl_xor(pm, 4);
      ps += __shfl_xor(ps, 1); ps += __shfl_xor(ps, 2); ps += __shfl_xor(ps, 4);
      if (q == 0) {
        out[2 * B_TOT + (size_t)(row0 + r) * 30 + t] = pm + dmub;
        out[32 * B_TOT + (size_t)(row0 + r) * 30 + t] = softplusf_(ps + dsigb);
      }
    }
  }
}

extern "C" void kernel_launch(void* const* d_in, const int* in_sizes, int n_in,
                              void* d_out, int out_size, void* d_ws, size_t ws_size,
                              hipStream_t stream) {
  (void)in_sizes; (void)n_in; (void)out_size;
  const float* x14      = (const float*)d_in[0];
  const float* fa_w     = (const float*)d_in[1];
  const float* fa_b     = (const float*)d_in[2];
  const float* enc_wih  = (const float*)d_in[3];
  const float* enc_whh  = (const float*)d_in[4];
  const float* enc_bih  = (const float*)d_in[5];
  const float* enc_bhh  = (const float*)d_in[6];
  const float* q_tok    = (const float*)d_in[7];
  const float* pool_win = (const float*)d_in[8];
  const float* pool_bin = (const float*)d_in[9];
  const float* pool_wout= (const float*)d_in[10];
  const float* pool_bout= (const float*)d_in[11];
  const float* mu_w     = (const float*)d_in[12];
  const float* mu_b     = (const float*)d_in[13];
  const float* sig_w    = (const float*)d_in[14];
  const float* sig_b    = (const float*)d_in[15];
  const float* dec_wih  = (const float*)d_in[16];
  const float* dec_whh  = (const float*)d_in[17];
  const float* dec_bih  = (const float*)d_in[18];
  const float* dec_bhh  = (const float*)d_in[19];
  const float* dmu_w    = (const float*)d_in[20];
  const float* dmu_b    = (const float*)d_in[21];
  const float* dsig_w   = (const float*)d_in[22];
  const float* dsig_b   = (const float*)d_in[23];
  char* ws = (char*)d_ws;

  hfn_prep<<<dim3(128), dim3(256), 0, stream>>>(fa_w, enc_wih, enc_whh, enc_bih, enc_bhh,
      q_tok, pool_win, pool_bin, pool_wout, dec_wih, dec_whh, dec_bih, dec_bhh, ws);
  if (ws_size >= XW_NEED) {
    hfn_attn<<<dim3(512 * 14), dim3(256), 0, stream>>>(x14, fa_b, ws);
    hfn_main<0><<<dim3(512), dim3(512), 0, stream>>>(x14, fa_b, pool_bin, pool_bout,
        mu_w, mu_b, sig_w, sig_b, dmu_w, dmu_b, dsig_w, dsig_b, ws, (float*)d_out);
  } else {
    hfn_main<1><<<dim3(512), dim3(512), 0, stream>>>(x14, fa_b, pool_bin, pool_bout,
        mu_w, mu_b, sig_w, sig_b, dmu_w, dmu_b, dsig_w, dsig_b, ws, (float*)d_out);
  }
}